// Round 6
// baseline (1456.148 us; speedup 1.0000x reference)
//
#include <hip/hip_runtime.h>
#include <cmath>
#include <cstdint>

// Problem constants (B=8, N=4096, C=1024, H=16, D=64, FF=4096)
#define MTOK 32768   // B*N tokens
#define CDIM 1024
#define SEQ  4096
#define NHEAD 16
#define HDIM 64
#define FFDIM 4096

typedef __attribute__((ext_vector_type(8))) short short8;   // 8 bf16 (4 VGPRs)
typedef __attribute__((ext_vector_type(4))) float f32x4;
typedef __attribute__((ext_vector_type(16))) float f32x16;  // 32x32 MFMA acc

static __device__ __forceinline__ float b2f(unsigned short u){
  union { unsigned int i; float f; } c; c.i = ((unsigned int)u)<<16; return c.f;
}
static __device__ __forceinline__ unsigned short f2b(float f){
  union { float f; unsigned int i; } c; c.f = f;
  return (unsigned short)((c.i + 0x7fffu + ((c.i>>16)&1u)) >> 16);  // RNE
}
// gelu_exact via A&S 7.1.26 erf (|eps|<=1.5e-7, far below bf16 quantum)
static __device__ __forceinline__ float fast_gelu(float v){
  float s = v*0.70710678118654752f;
  float a = fabsf(s);
  float t = 1.f/(1.f + 0.3275911f*a);
  float p = t*(0.254829592f + t*(-0.284496736f + t*(1.421413741f +
            t*(-1.453152027f + t*1.061405429f))));
  float erfa = 1.f - p*__expf(-a*a);
  float er = (s<0.f)? -erfa : erfa;
  return 0.5f*v*(1.f+er);
}
// async global->LDS, 16B/lane; LDS dest = wave-uniform base + lane*16
static __device__ __forceinline__ void async16(const void* g, void* l){
  __builtin_amdgcn_global_load_lds((const __attribute__((address_space(1))) void*)g,
                                   (__attribute__((address_space(3))) void*)l, 16, 0, 0);
}

// ---------------- mask dtype detection + decode ----------------
__global__ void detect_mask_kernel(const unsigned int* __restrict__ m, int* __restrict__ flag){
  __shared__ int any;
  if(threadIdx.x==0) any=0;
  __syncthreads();
  int loc=0;
  for(int i=threadIdx.x;i<8192;i+=256) if(m[i]>1u) loc=1;
  if(loc) atomicOr(&any,1);
  __syncthreads();
  if(threadIdx.x==0) *flag=any;
}
__global__ void decode_mask_kernel(const void* __restrict__ m, const int* __restrict__ flag,
                                   float* __restrict__ validf){
  int i = blockIdx.x*256 + threadIdx.x;   // grid covers MTOK exactly
  int pad = (*flag) ? (int)((const unsigned char*)m)[i] : ((const int*)m)[i];
  validf[i] = pad ? 0.f : 1.f;
}

// ---------------- fp32 -> bf16 cast, all four weights in one launch ----------------
__global__ void cast_all_kernel(const float* __restrict__ a, const float* __restrict__ b,
                                const float* __restrict__ c, const float* __restrict__ d,
                                unsigned short* __restrict__ oa, unsigned short* __restrict__ ob,
                                unsigned short* __restrict__ oc, unsigned short* __restrict__ od){
  long i = ((long)blockIdx.x*256 + threadIdx.x)*4;   // total 12582912 elems -> 12288 blocks
  const float* x; unsigned short* y; long off;
  if(i < 3145728){ x=a; y=oa; off=i; }
  else if(i < 4194304){ x=b; y=ob; off=i-3145728; }
  else if(i < 8388608){ x=c; y=oc; off=i-4194304; }
  else { x=d; y=od; off=i-8388608; }
  float4 v = *(const float4*)(x+off);
  ushort4 o; o.x=f2b(v.x); o.y=f2b(v.y); o.z=f2b(v.z); o.w=f2b(v.w);
  *(ushort4*)(y+off)=o;
}

// ---------------- LayerNorm (C=1024) -> bf16 ----------------
__global__ __launch_bounds__(256) void ln_kernel(const float* __restrict__ x,
    const float* __restrict__ g, const float* __restrict__ bt, unsigned short* __restrict__ out){
  int row = blockIdx.x, t = threadIdx.x;
  const float* xr = x + (size_t)row*CDIM;
  float4 v = *(const float4*)(xr + t*4);
  float s1 = v.x+v.y+v.z+v.w;
  float s2 = v.x*v.x+v.y*v.y+v.z*v.z+v.w*v.w;
  #pragma unroll
  for(int off=32; off>0; off>>=1){ s1+=__shfl_down(s1,off); s2+=__shfl_down(s2,off); }
  __shared__ float a1[4], a2[4];
  __shared__ float mu_s, rs_s;
  if((t&63)==0){ a1[t>>6]=s1; a2[t>>6]=s2; }
  __syncthreads();
  if(t==0){
    float u1=a1[0]+a1[1]+a1[2]+a1[3], u2=a2[0]+a2[1]+a2[2]+a2[3];
    float mu=u1*(1.f/CDIM);
    mu_s=mu; rs_s=rsqrtf(u2*(1.f/CDIM)-mu*mu+1e-5f);
  }
  __syncthreads();
  float mu=mu_s, rs=rs_s;
  float4 gg=*(const float4*)(g+t*4), bb=*(const float4*)(bt+t*4);
  ushort4 o;
  o.x=f2b((v.x-mu)*rs*gg.x+bb.x);
  o.y=f2b((v.y-mu)*rs*gg.y+bb.y);
  o.z=f2b((v.z-mu)*rs*gg.z+bb.z);
  o.w=f2b((v.w-mu)*rs*gg.w+bb.w);
  *(ushort4*)(out+(size_t)row*CDIM+t*4)=o;
}

// ---------------- GEMM: C[M,N] = A[M,K] * Bw[N,K]^T, bf16 in, fused epilogue ----
// 128x128 m97-structure; LDS XOR-chunk swizzle, global_load_lds x16; grouped
// XCD walk (8 A-panels x 4 B-panels per XCD concurrent footprint <= L2).
// Inner loop uses mfma_f32_32x32x16_bf16 (16 MFMA/wave/K-tile vs 32 for 16x16:
// half the issue slots, ~17% fewer matrix-pipe cycles; ds_read pattern and
// XOR swizzle identical since row&7 == lane&7 for both lane&15 and lane&31).
// C/D layout (HW-verified m74/m101): col=lane&31, row=(reg&3)+8*(reg>>2)+4*(lane>>5).
// MODE 0: QKV -> q: phi(q) -> Cb[m][1024]; k: phi(k)*valid -> Kt[bh][d][pos];
//         v: v*valid -> Vt[bh][d][pos]  (K/V stored TRANSPOSED for MFMA kvz)
// MODE 1: XRES -> Cf[m,N] = acc + bias + extra[m,N]   (out-proj + residual, Cf=d_out)
// MODE 2: GELU -> Cb[m,N] = bf16(gelu_exact(acc+bias))
// MODE 3: ADD  -> Cf[m,N] += acc + bias               (FFN2 accumulate into x)
template<int MODE>
__global__ __launch_bounds__(256,4) void gemm_bt(
    const unsigned short* __restrict__ A, const unsigned short* __restrict__ Bw,
    const float* __restrict__ bias, const float* __restrict__ extra,
    float* __restrict__ Cf, unsigned short* __restrict__ Cb,
    unsigned short* __restrict__ Kt, unsigned short* __restrict__ Vt,
    int M, int N, int K)
{
  __shared__ __align__(16) unsigned short As[128*64];
  __shared__ __align__(16) unsigned short Bs[128*64];
  const int tid = threadIdx.x;
  const int wave = tid>>6, lane = tid&63;
  const int wm = wave>>1, wn = wave&1;          // 2x2 wave grid, 64x64 per wave
  // XCD-aware grouped remap (gridDim.y==256, gridDim.x%4==0, total%8==0)
  const int gx  = gridDim.x;
  const int f   = blockIdx.y * gx + blockIdx.x;
  const int xcd = f & 7;
  const int kk  = f >> 3;
  const int idx = kk & 31, g = kk >> 5;
  const int nq  = gx >> 2;
  const int gxq = g % nq, gy = g / nq;
  const int nx  = gxq*4 + (idx>>3);
  const int ny  = (gy*8 + (idx&7))*8 + xcd;
  const int m0 = ny*128, n0 = nx*128;
  const int lrow = lane>>3;                     // 0..7 rows within a wave-op
  const int gcol = (((lane&7) ^ lrow))*8;       // swizzled global chunk for staging

  f32x16 acc[2][2];
  #pragma unroll
  for(int i=0;i<2;i++)
    #pragma unroll
    for(int j=0;j<2;j++) acc[i][j]=(f32x16)(0.f);

  const int ar = wm*64 + (lane&31);             // A frag row in tile (+am*32)
  const int br = wn*64 + (lane&31);             // B frag row in tile (+bn*32)
  const int kg = lane>>5;                       // k-group (0..1), 8 bf16 each
  const int xorv = lane&7;                      // row&7 == lane&7 for all frags

  for(int kt=0; kt<K; kt+=64){
    #pragma unroll
    for(int it=0; it<4; it++){
      int wo = wave*4+it;                       // wave-op 0..15, 8 rows each
      int r  = wo*8 + lrow;
      async16(A  + (size_t)(m0+r)*K + kt + gcol, (void*)&As[wo*512]);
      async16(Bw + (size_t)(n0+r)*K + kt + gcol, (void*)&Bs[wo*512]);
    }
    __syncthreads();   // compiler drains vmcnt before s_barrier -> tiles ready
    #pragma unroll
    for(int t=0; t<4; t++){                     // K=16 steps: k in [16t,16t+16)
      const int ch = ((2*t + kg) ^ xorv)*8;     // swizzled LDS chunk offset
      short8 a0 = *(const short8*)&As[(ar   )*64 + ch];
      short8 a1 = *(const short8*)&As[(ar+32)*64 + ch];
      short8 b0 = *(const short8*)&Bs[(br   )*64 + ch];
      short8 b1 = *(const short8*)&Bs[(br+32)*64 + ch];
      acc[0][0]=__builtin_amdgcn_mfma_f32_32x32x16_bf16(a0,b0,acc[0][0],0,0,0);
      acc[0][1]=__builtin_amdgcn_mfma_f32_32x32x16_bf16(a0,b1,acc[0][1],0,0,0);
      acc[1][0]=__builtin_amdgcn_mfma_f32_32x32x16_bf16(a1,b0,acc[1][0],0,0,0);
      acc[1][1]=__builtin_amdgcn_mfma_f32_32x32x16_bf16(a1,b1,acc[1][1],0,0,0);
    }
    __syncthreads();
  }
  // epilogue: C/D layout col=lane&31, row=(reg&3)+8*(reg>>2)+4*(lane>>5)
  const int col5 = lane&31;
  const int rhi  = 4*(lane>>5);
  if(MODE==0){
    #pragma unroll
    for(int am=0;am<2;am++){
      #pragma unroll
      for(int q=0;q<4;q++){
        int mrow = m0 + wm*64 + am*32 + q*8 + rhi;     // 4 consecutive rows
        float4 vld = *(const float4*)(extra + mrow);   // validf, mrow%4==0
        float vv[4] = {vld.x, vld.y, vld.z, vld.w};
        #pragma unroll
        for(int bn=0;bn<2;bn++){
          int n = n0 + wn*64 + bn*32 + col5;
          float bs = bias[n];
          int part = n>>10;                            // 0=q,1=k,2=v (tile never straddles)
          if(part==0){
            #pragma unroll
            for(int i=0;i<4;i++){
              float v = acc[am][bn][q*4+i] + bs;
              float p = (v>0.f)? (v+1.f) : __expf(v);  // phi = elu+1
              Cb[(size_t)(mrow+i)*1024 + n] = f2b(p);  // qb[m][1024]
            }
          } else {
            int d = n & 63, hh = (n>>6) & 15;
            int bb_ = mrow >> 12, pos = mrow & 4095;   // pos%4==0 -> aligned ushort4
            unsigned short* dst = (part==1? Kt : Vt)
                + (((size_t)(bb_*16+hh)*64 + d)*SEQ + pos);
            ushort4 o;
            #pragma unroll
            for(int i=0;i<4;i++){
              float v = acc[am][bn][q*4+i] + bs;
              float r = (part==1)? (((v>0.f)?(v+1.f):__expf(v))*vv[i]) : (v*vv[i]);
              ((unsigned short*)&o)[i] = f2b(r);
            }
            *(ushort4*)dst = o;                        // 4 consecutive seq positions
          }
        }
      }
    }
  } else {
    #pragma unroll
    for(int am=0;am<2;am++){
      #pragma unroll
      for(int bn=0;bn<2;bn++){
        int n = n0 + wn*64 + bn*32 + col5;
        float bs = bias[n];
        #pragma unroll
        for(int reg=0;reg<16;reg++){
          int m = m0 + wm*64 + am*32 + (reg&3) + 8*(reg>>2) + rhi;
          float v = acc[am][bn][reg] + bs;
          if(MODE==1){
            size_t off=(size_t)m*N+n;
            Cf[off] = v + extra[off];
          } else if(MODE==2){
            Cb[(size_t)m*N+n] = f2b(fast_gelu(v));
          } else {
            size_t off=(size_t)m*N+n;
            Cf[off] += v;
          }
        }
      }
    }
  }
}

// ---------------- kvT[e][d] = sum_n v[n][e]*kf[n][d], z[d] = sum_n kf[n][d] ----
// MFMA over K=n. A-operand = Vt rows (e), B-operand = Kt rows (d) -- both stored
// [bh][64][4096] row-major-by-n == exactly the gemm_bt fragment pattern.
// One wave per block; 16 n-slices of 256 per (b,h), 2 serial rounds of 2x64-n
// chunks (32KB LDS). Single-wave block: no barriers, but lgkmcnt(0) before
// round 2's stage (LDS-DMA writes are NOT ordered vs pending ds_reads).
__global__ __launch_bounds__(64) void kvz_mfma_kernel(
    const unsigned short* __restrict__ Kt, const unsigned short* __restrict__ Vt,
    float* __restrict__ kvp, float* __restrict__ zp)
{
  __shared__ __align__(16) unsigned short Ks[2][64*64];
  __shared__ __align__(16) unsigned short Vs[2][64*64];
  const int blk = blockIdx.x;             // 0..2047
  const int bh = blk>>4, kcn = blk&15;    // n-slice of 256
  const int n0 = kcn*256;
  const int lane = threadIdx.x;
  const int r8 = lane>>3;
  const int gch = ((lane&7) ^ r8)*8;
  const size_t base = (size_t)bh*64*SEQ + n0 + gch;
  f32x4 acc[4][4];
  #pragma unroll
  for(int i=0;i<4;i++)
    #pragma unroll
    for(int j=0;j<4;j++) acc[i][j]=(f32x4)(0.f);
  float zacc[4]={0.f,0.f,0.f,0.f};
  const int l15 = lane&15, kc4 = lane>>4, x7 = lane&7;
  for(int rr=0; rr<2; rr++){
    if(rr) asm volatile("s_waitcnt lgkmcnt(0)" ::: "memory");  // ds_reads done before DMA overwrite
    #pragma unroll
    for(int t=0;t<2;t++){
      int cc = rr*2 + t;
      #pragma unroll
      for(int wo=0;wo<8;wo++){
        int r = wo*8 + r8;
        async16(Kt + base + (size_t)r*SEQ + cc*64, (void*)&Ks[t][wo*512]);
        async16(Vt + base + (size_t)r*SEQ + cc*64, (void*)&Vs[t][wo*512]);
      }
    }
    asm volatile("s_waitcnt vmcnt(0)" ::: "memory");
    #pragma unroll
    for(int t=0;t<2;t++){
      #pragma unroll
      for(int ks=0; ks<2; ks++){
        const int ch = ((ks*4 + kc4) ^ x7)*8;
        short8 a[4], b[4];
        #pragma unroll
        for(int i=0;i<4;i++) a[i]=*(const short8*)&Vs[t][(l15+i*16)*64 + ch];
        #pragma unroll
        for(int j=0;j<4;j++) b[j]=*(const short8*)&Ks[t][(l15+j*16)*64 + ch];
        #pragma unroll
        for(int j=0;j<4;j++)
          #pragma unroll
          for(int e8=0;e8<8;e8++) zacc[j] += b2f((unsigned short)b[j][e8]);
        #pragma unroll
        for(int i=0;i<4;i++)
          #pragma unroll
          for(int j=0;j<4;j++)
            acc[i][j]=__builtin_amdgcn_mfma_f32_16x16x32_bf16(a[i],b[j],acc[i][j],0,0,0);
      }
    }
  }
  // z: lanes l, l+16, l+32, l+48 hold disjoint n-chunks of d = j*16+l15
  #pragma unroll
  for(int j=0;j<4;j++){
    float v = zacc[j];
    v += __shfl_down(v, 32);
    v += __shfl_down(v, 16);
    if(lane<16) zp[(size_t)blk*64 + j*16 + lane] = v;
  }
  float* kvd = kvp + (size_t)blk*4096;
  #pragma unroll
  for(int i=0;i<4;i++)
    #pragma unroll
    for(int j=0;j<4;j++)
      #pragma unroll
      for(int r=0;r<4;r++)
        kvd[(i*16 + kc4*4 + r)*64 + j*16 + l15] = acc[i][j][r];
}

// reduce 16 partials -> kvtb[bh][80][64] bf16: rows 0..63 kvT, row 64 = z, 65..79 = 0
__global__ void kvz_reduce_kernel(const float* __restrict__ kvp, const float* __restrict__ zp,
                                  unsigned short* __restrict__ kvtb){
  int bh = blockIdx.x, t = threadIdx.x;
  for(int idx=t; idx<5120; idx+=256){
    int e = idx>>6, d = idx&63;
    float s = 0.f;
    if(e < 64){
      for(int c=0;c<16;c++) s += kvp[((size_t)bh*16+c)*4096 + e*64 + d];
    } else if(e == 64){
      for(int c=0;c<16;c++) s += zp[((size_t)bh*16+c)*64 + d];
    }
    kvtb[(size_t)bh*5120 + idx] = f2b(s);
  }
}

// ---------------- y[m][e] = (qf @ kvT^T)/max(qf.z,eps) via MFMA, K=64 ----------
// B-tile = kvtb[bh][80][64]: rows 0..63 -> y cols, row 64 -> denominator col.
__global__ __launch_bounds__(256) void y_gemm_kernel(
    const unsigned short* __restrict__ qb, const unsigned short* __restrict__ kvtb,
    unsigned short* __restrict__ ybuf)
{
  __shared__ __align__(16) unsigned short As[128*64];
  __shared__ __align__(16) unsigned short Bs[80*64];
  const int tid = threadIdx.x, lane = tid&63, wave = tid>>6;
  const int bh = blockIdx.y, b = bh>>4, h = bh&15;
  const int m0 = blockIdx.x*128;
  const int r8 = lane>>3, gch = ((lane&7)^r8)*8;
  const unsigned short* qbase = qb + ((size_t)(b*SEQ + m0))*1024 + h*64 + gch;
  #pragma unroll
  for(int it=0; it<4; it++){
    int wo = wave*4 + it, r = wo*8 + r8;
    async16(qbase + (size_t)r*1024, (void*)&As[wo*512]);
  }
  const unsigned short* kvb = kvtb + (size_t)bh*5120 + gch;
  #pragma unroll
  for(int it=0; it<3; it++){
    int wo = wave + it*4;
    if(wo < 10){ int r = wo*8 + r8; async16(kvb + r*64, (void*)&Bs[wo*512]); }
  }
  __syncthreads();
  const int l15 = lane&15, kc4 = lane>>4, x7 = lane&7;
  f32x4 acc[2][5];
  #pragma unroll
  for(int i=0;i<2;i++)
    #pragma unroll
    for(int j=0;j<5;j++) acc[i][j]=(f32x4)(0.f);
  #pragma unroll
  for(int ks=0; ks<2; ks++){
    const int ch = ((ks*4 + kc4) ^ x7)*8;
    short8 a[2], bb[5];
    #pragma unroll
    for(int i=0;i<2;i++) a[i]=*(const short8*)&As[(wave*32 + i*16 + l15)*64 + ch];
    #pragma unroll
    for(int j=0;j<5;j++) bb[j]=*(const short8*)&Bs[(j*16 + l15)*64 + ch];
    #pragma unroll
    for(int i=0;i<2;i++)
      #pragma unroll
      for(int j=0;j<5;j++)
        acc[i][j]=__builtin_amdgcn_mfma_f32_16x16x32_bf16(a[i],bb[j],acc[i][j],0,0,0);
  }
  #pragma unroll
  for(int i=0;i<2;i++){
    #pragma unroll
    for(int r=0;r<4;r++){
      float den = __shfl(acc[i][4][r], lane & 48);   // col 64 lives at l15==0
      float inv = 1.f/fmaxf(den, 1e-6f);
      size_t m = (size_t)(b*SEQ + m0 + wave*32 + i*16 + kc4*4 + r);
      #pragma unroll
      for(int j=0;j<4;j++)
        ybuf[m*1024 + h*64 + j*16 + l15] = f2b(acc[i][j][r]*inv);
    }
  }
}

extern "C" void kernel_launch(void* const* d_in, const int* in_sizes, int n_in,
                              void* d_out, int out_size, void* d_ws, size_t ws_size,
                              hipStream_t stream)
{
  const float* src   = (const float*)d_in[0];
  const void*  mask  = d_in[1];
  const float* qkv_w = (const float*)d_in[2];
  const float* qkv_b = (const float*)d_in[3];
  const float* out_w = (const float*)d_in[4];
  const float* out_b = (const float*)d_in[5];
  const float* w1    = (const float*)d_in[6];
  const float* b1    = (const float*)d_in[7];
  const float* w2    = (const float*)d_in[8];
  const float* b2    = (const float*)d_in[9];
  const float* ln1g  = (const float*)d_in[10];
  const float* ln1b  = (const float*)d_in[11];
  const float* ln2g  = (const float*)d_in[12];
  const float* ln2b  = (const float*)d_in[13];
  float* out = (float*)d_out;
  char* ws = (char*)d_ws;

  // workspace layout
  size_t o = 0;
  int* flag = (int*)(ws);                         o += 256;
  float* validf = (float*)(ws+o);                 o += (size_t)MTOK*4;
  unsigned short* wqb = (unsigned short*)(ws+o);  o += (size_t)3072*1024*2;
  unsigned short* wob = (unsigned short*)(ws+o);  o += (size_t)1024*1024*2;
  unsigned short* w1b = (unsigned short*)(ws+o);  o += (size_t)4096*1024*2;
  unsigned short* w2b = (unsigned short*)(ws+o);  o += (size_t)1024*4096*2;
  unsigned short* bufA = (unsigned short*)(ws+o); o += (size_t)MTOK*1024*2;       // ln1 -> y -> ln2
  char* R = ws+o;                                 o += (size_t)MTOK*4096*2;       // attn bufs, then h
  unsigned short* qb  = (unsigned short*)R;                                        // 67 MB phi(q) [m][1024]
  unsigned short* ktb = (unsigned short*)(R + (size_t)MTOK*1024*2);                // 67 MB K^T [bh][64][4096]
  unsigned short* vtb = (unsigned short*)(R + (size_t)MTOK*2048*2);                // 67 MB V^T
  float* kvp = (float*)(R + (size_t)MTOK*3072*2);                                  // 33.5 MB partials (fits R tail)
  unsigned short* hbuf = (unsigned short*)R;                                       // FFN h aliases R
  float* zp = (float*)(ws+o);                     o += (size_t)2048*64*4;          // 0.5 MB z partials
  unsigned short* kvtb = (unsigned short*)(ws+o); o += (size_t)128*5120*2;         // 1.25 MB kvT+z bf16

  detect_mask_kernel<<<1,256,0,stream>>>((const unsigned int*)mask, flag);
  decode_mask_kernel<<<MTOK/256,256,0,stream>>>(mask, flag, validf);
  cast_all_kernel<<<12288,256,0,stream>>>(qkv_w, out_w, w1, w2, wqb, wob, w1b, w2b);

  ln_kernel<<<MTOK,256,0,stream>>>(src, ln1g, ln1b, bufA);
  gemm_bt<0><<<dim3(3072/128, MTOK/128),256,0,stream>>>(bufA, wqb, qkv_b, validf, nullptr, qb, ktb, vtb, MTOK,3072,1024);
  kvz_mfma_kernel<<<2048,64,0,stream>>>(ktb, vtb, kvp, zp);
  kvz_reduce_kernel<<<128,256,0,stream>>>(kvp, zp, kvtb);
  y_gemm_kernel<<<dim3(SEQ/128,128),256,0,stream>>>(qb, kvtb, bufA);
  gemm_bt<1><<<dim3(1024/128, MTOK/128),256,0,stream>>>(bufA, wob, out_b, src, out, nullptr, nullptr, nullptr, MTOK,1024,1024);
  ln_kernel<<<MTOK,256,0,stream>>>(out, ln2g, ln2b, bufA);
  gemm_bt<2><<<dim3(4096/128, MTOK/128),256,0,stream>>>(bufA, w1b, b1, nullptr, nullptr, hbuf, nullptr, nullptr, MTOK,4096,1024);
  gemm_bt<3><<<dim3(1024/128, MTOK/128),256,0,stream>>>(hbuf, w2b, b2, nullptr, out, nullptr, nullptr, nullptr, MTOK,1024,4096);
}

// Round 7
// 1307.783 us; speedup vs baseline: 1.1134x; 1.1134x over previous
//
#include <hip/hip_runtime.h>
#include <cmath>
#include <cstdint>

// Problem constants (B=8, N=4096, C=1024, H=16, D=64, FF=4096)
#define MTOK 32768   // B*N tokens
#define CDIM 1024
#define SEQ  4096
#define NHEAD 16
#define HDIM 64
#define FFDIM 4096

typedef __attribute__((ext_vector_type(8))) short short8;   // 8 bf16 (4 VGPRs)
typedef __attribute__((ext_vector_type(4))) float f32x4;

static __device__ __forceinline__ float b2f(unsigned short u){
  union { unsigned int i; float f; } c; c.i = ((unsigned int)u)<<16; return c.f;
}
static __device__ __forceinline__ unsigned short f2b(float f){
  union { float f; unsigned int i; } c; c.f = f;
  return (unsigned short)((c.i + 0x7fffu + ((c.i>>16)&1u)) >> 16);  // RNE
}
// gelu_exact via A&S 7.1.26 erf (|eps|<=1.5e-7, far below bf16 quantum)
static __device__ __forceinline__ float fast_gelu(float v){
  float s = v*0.70710678118654752f;
  float a = fabsf(s);
  float t = 1.f/(1.f + 0.3275911f*a);
  float p = t*(0.254829592f + t*(-0.284496736f + t*(1.421413741f +
            t*(-1.453152027f + t*1.061405429f))));
  float erfa = 1.f - p*__expf(-a*a);
  float er = (s<0.f)? -erfa : erfa;
  return 0.5f*v*(1.f+er);
}
// async global->LDS, 16B/lane; LDS dest = wave-uniform base + lane*16
static __device__ __forceinline__ void async16(const void* g, void* l){
  __builtin_amdgcn_global_load_lds((const __attribute__((address_space(1))) void*)g,
                                   (__attribute__((address_space(3))) void*)l, 16, 0, 0);
}

// ---------------- mask decode with per-block dtype detection ----------------
// Each block redundantly scans the first 32KB of the mask as uints (L2-resident
// after the first block): any value >1 => mask is bool (1B/elem), else int32.
// Identical decision logic to the old 1-block detect kernel, minus the extra
// launch + queue serialization.
__global__ void decode_mask_kernel(const void* __restrict__ m, float* __restrict__ validf){
  __shared__ int any;
  if(threadIdx.x==0) any=0;
  __syncthreads();
  const unsigned int* mu = (const unsigned int*)m;
  int loc=0;
  for(int i=threadIdx.x;i<8192;i+=256) if(mu[i]>1u) loc=1;
  if(loc) atomicOr(&any,1);
  __syncthreads();
  int i = blockIdx.x*256 + threadIdx.x;   // grid covers MTOK exactly
  int pad = any ? (int)((const unsigned char*)m)[i] : ((const int*)m)[i];
  validf[i] = pad ? 0.f : 1.f;
}

// ---------------- fp32 -> bf16 cast, all four weights in one launch ----------------
__global__ void cast_all_kernel(const float* __restrict__ a, const float* __restrict__ b,
                                const float* __restrict__ c, const float* __restrict__ d,
                                unsigned short* __restrict__ oa, unsigned short* __restrict__ ob,
                                unsigned short* __restrict__ oc, unsigned short* __restrict__ od){
  long i = ((long)blockIdx.x*256 + threadIdx.x)*4;   // total 12582912 elems -> 12288 blocks
  const float* x; unsigned short* y; long off;
  if(i < 3145728){ x=a; y=oa; off=i; }
  else if(i < 4194304){ x=b; y=ob; off=i-3145728; }
  else if(i < 8388608){ x=c; y=oc; off=i-4194304; }
  else { x=d; y=od; off=i-8388608; }
  float4 v = *(const float4*)(x+off);
  ushort4 o; o.x=f2b(v.x); o.y=f2b(v.y); o.z=f2b(v.z); o.w=f2b(v.w);
  *(ushort4*)(y+off)=o;
}

// ---------------- LayerNorm (C=1024) -> bf16 ----------------
__global__ __launch_bounds__(256) void ln_kernel(const float* __restrict__ x,
    const float* __restrict__ g, const float* __restrict__ bt, unsigned short* __restrict__ out){
  int row = blockIdx.x, t = threadIdx.x;
  const float* xr = x + (size_t)row*CDIM;
  float4 v = *(const float4*)(xr + t*4);
  float s1 = v.x+v.y+v.z+v.w;
  float s2 = v.x*v.x+v.y*v.y+v.z*v.z+v.w*v.w;
  #pragma unroll
  for(int off=32; off>0; off>>=1){ s1+=__shfl_down(s1,off); s2+=__shfl_down(s2,off); }
  __shared__ float a1[4], a2[4];
  __shared__ float mu_s, rs_s;
  if((t&63)==0){ a1[t>>6]=s1; a2[t>>6]=s2; }
  __syncthreads();
  if(t==0){
    float u1=a1[0]+a1[1]+a1[2]+a1[3], u2=a2[0]+a2[1]+a2[2]+a2[3];
    float mu=u1*(1.f/CDIM);
    mu_s=mu; rs_s=rsqrtf(u2*(1.f/CDIM)-mu*mu+1e-5f);
  }
  __syncthreads();
  float mu=mu_s, rs=rs_s;
  float4 gg=*(const float4*)(g+t*4), bb=*(const float4*)(bt+t*4);
  ushort4 o;
  o.x=f2b((v.x-mu)*rs*gg.x+bb.x);
  o.y=f2b((v.y-mu)*rs*gg.y+bb.y);
  o.z=f2b((v.z-mu)*rs*gg.z+bb.z);
  o.w=f2b((v.w-mu)*rs*gg.w+bb.w);
  *(ushort4*)(out+(size_t)row*CDIM+t*4)=o;
}

// ---------------- GEMM: C[M,N] = A[M,K] * Bw[N,K]^T, bf16 in, fused epilogue ----
// known-good 128x128 m97-structure; LDS XOR-chunk swizzle, global_load_lds x16.
// XCD walk: per XCD, blocks grouped into 8(ny) x 4(nx) super-tiles so the ~32
// concurrently-resident blocks touch 8 A-panels + 4 B-panels (3 MB @ K=1024)
// <= 4 MB XCD L2.
// 16x16x32 MFMA only: the 32x32 variant has a structural LDS bank conflict on
// this layout (r5: SQ_LDS_BANK_CONFLICT 0 -> 3.4e7, -20% dur). Do not revisit.
// MODE 0: QKV -> q: phi(q) -> Cb[m][1024]; k: phi(k)*valid -> Kt[bh][d][pos];
//         v: v*valid -> Vt[bh][d][pos]  (K/V stored TRANSPOSED for MFMA kvz)
// MODE 1: XRES -> Cf[m,N] = acc + bias + extra[m,N]   (out-proj + residual, Cf=d_out)
// MODE 2: GELU -> Cb[m,N] = bf16(gelu_exact(acc+bias))
// MODE 3: ADD  -> Cf[m,N] += acc + bias               (FFN2 accumulate into x)
template<int MODE>
__global__ __launch_bounds__(256,2) void gemm_bt(
    const unsigned short* __restrict__ A, const unsigned short* __restrict__ Bw,
    const float* __restrict__ bias, const float* __restrict__ extra,
    float* __restrict__ Cf, unsigned short* __restrict__ Cb,
    unsigned short* __restrict__ Kt, unsigned short* __restrict__ Vt,
    int M, int N, int K)
{
  __shared__ __align__(16) unsigned short As[128*64];
  __shared__ __align__(16) unsigned short Bs[128*64];
  const int tid = threadIdx.x;
  const int wave = tid>>6, lane = tid&63;
  const int wm = wave>>1, wn = wave&1;          // 2x2 wave grid, 64x64 per wave
  // XCD-aware grouped remap (gridDim.y==256, gridDim.x%4==0, total%8==0)
  const int gx  = gridDim.x;
  const int f   = blockIdx.y * gx + blockIdx.x;
  const int xcd = f & 7;
  const int kk  = f >> 3;
  const int idx = kk & 31, g = kk >> 5;
  const int nq  = gx >> 2;
  const int gxq = g % nq, gy = g / nq;
  const int nx  = gxq*4 + (idx>>3);
  const int ny  = (gy*8 + (idx&7))*8 + xcd;
  const int m0 = ny*128, n0 = nx*128;
  const int lrow = lane>>3;                     // 0..7 rows within a wave-op
  const int gcol = (((lane&7) ^ lrow))*8;       // swizzled global chunk for staging

  f32x4 acc[4][4];
  #pragma unroll
  for(int i=0;i<4;i++)
    #pragma unroll
    for(int j=0;j<4;j++) acc[i][j]=(f32x4)(0.f);

  const int ar = wm*64 + (lane&15);             // A frag row in tile
  const int br = wn*64 + (lane&15);             // B frag row in tile
  const int kc = lane>>4;                       // k chunk sub-index (0..3)
  const int xorv = lane&7;                      // row&7 == lane&7 for all frags

  for(int kt=0; kt<K; kt+=64){
    #pragma unroll
    for(int it=0; it<4; it++){
      int wo = wave*4+it;                       // wave-op 0..15, 8 rows each
      int r  = wo*8 + lrow;
      async16(A  + (size_t)(m0+r)*K + kt + gcol, (void*)&As[wo*512]);
      async16(Bw + (size_t)(n0+r)*K + kt + gcol, (void*)&Bs[wo*512]);
    }
    __syncthreads();   // compiler drains vmcnt before s_barrier -> tiles ready
    #pragma unroll
    for(int ks=0; ks<2; ks++){
      const int ch = ((ks*4 + kc) ^ xorv)*8;    // swizzled LDS chunk offset
      short8 a[4], b[4];
      #pragma unroll
      for(int i=0;i<4;i++){
        a[i]=*(const short8*)&As[(ar+i*16)*64 + ch];
        b[i]=*(const short8*)&Bs[(br+i*16)*64 + ch];
      }
      #pragma unroll
      for(int i=0;i<4;i++)
        #pragma unroll
        for(int j=0;j<4;j++)
          acc[i][j]=__builtin_amdgcn_mfma_f32_16x16x32_bf16(a[i],b[j],acc[i][j],0,0,0);
    }
    __syncthreads();
  }
  // epilogue: C/D layout col=lane&15, row=(lane>>4)*4+reg
  const int rbase = m0 + wm*64 + (lane>>4)*4;
  const int cbase = n0 + wn*64 + (lane&15);
  if(MODE==0){
    #pragma unroll
    for(int mi=0;mi<4;mi++){
      int mrow = rbase + mi*16;
      float4 vld = *(const float4*)(extra + mrow);   // validf, mrow%4==0
      float vv[4] = {vld.x, vld.y, vld.z, vld.w};
      #pragma unroll
      for(int ni=0;ni<4;ni++){
        int n = cbase + ni*16;
        float bs = bias[n];
        int part = n>>10;                            // 0=q,1=k,2=v (tile never straddles)
        if(part==0){
          #pragma unroll
          for(int i=0;i<4;i++){
            float v = acc[mi][ni][i] + bs;
            float p = (v>0.f)? (v+1.f) : __expf(v);  // phi = elu+1
            Cb[(size_t)(mrow+i)*1024 + n] = f2b(p);  // qb[m][1024]
          }
        } else {
          int d = n & 63, hh = (n>>6) & 15;
          int bb_ = mrow >> 12, pos = mrow & 4095;   // pos%4==0 -> aligned ushort4
          unsigned short* dst = (part==1? Kt : Vt)
              + (((size_t)(bb_*16+hh)*64 + d)*SEQ + pos);
          ushort4 o;
          #pragma unroll
          for(int i=0;i<4;i++){
            float v = acc[mi][ni][i] + bs;
            float r = (part==1)? (((v>0.f)?(v+1.f):__expf(v))*vv[i]) : (v*vv[i]);
            ((unsigned short*)&o)[i] = f2b(r);
          }
          *(ushort4*)dst = o;                        // 4 consecutive seq positions
        }
      }
    }
  } else {
    #pragma unroll
    for(int mi=0;mi<4;mi++){
      #pragma unroll
      for(int i=0;i<4;i++){
        int m = rbase + mi*16 + i;
        #pragma unroll
        for(int ni=0;ni<4;ni++){
          int n = cbase + ni*16;
          float v = acc[mi][ni][i] + bias[n];
          if(MODE==1){
            size_t off=(size_t)m*N+n;
            Cf[off] = v + extra[off];
          } else if(MODE==2){
            Cb[(size_t)m*N+n] = f2b(fast_gelu(v));
          } else {
            size_t off=(size_t)m*N+n;
            Cf[off] += v;
          }
        }
      }
    }
  }
}

// ---------------- kvT[e][d] = sum_n v[n][e]*kf[n][d], z[d] = sum_n kf[n][d] ----
// MFMA over K=n. A-operand = Vt rows (e), B-operand = Kt rows (d) -- both stored
// [bh][64][4096] row-major-by-n == exactly the gemm_bt fragment pattern.
// One wave per block; 16 n-slices of 256 per (b,h), 2 serial rounds of 2x64-n
// chunks (32KB LDS). Single-wave block: no barriers, but lgkmcnt(0) before
// round 2's stage (LDS-DMA writes are NOT ordered vs pending ds_reads).
__global__ __launch_bounds__(64) void kvz_mfma_kernel(
    const unsigned short* __restrict__ Kt, const unsigned short* __restrict__ Vt,
    float* __restrict__ kvp, float* __restrict__ zp)
{
  __shared__ __align__(16) unsigned short Ks[2][64*64];
  __shared__ __align__(16) unsigned short Vs[2][64*64];
  const int blk = blockIdx.x;             // 0..2047
  const int bh = blk>>4, kcn = blk&15;    // n-slice of 256
  const int n0 = kcn*256;
  const int lane = threadIdx.x;
  const int r8 = lane>>3;
  const int gch = ((lane&7) ^ r8)*8;
  const size_t base = (size_t)bh*64*SEQ + n0 + gch;
  f32x4 acc[4][4];
  #pragma unroll
  for(int i=0;i<4;i++)
    #pragma unroll
    for(int j=0;j<4;j++) acc[i][j]=(f32x4)(0.f);
  float zacc[4]={0.f,0.f,0.f,0.f};
  const int l15 = lane&15, kc4 = lane>>4, x7 = lane&7;
  for(int rr=0; rr<2; rr++){
    if(rr) asm volatile("s_waitcnt lgkmcnt(0)" ::: "memory");  // ds_reads done before DMA overwrite
    #pragma unroll
    for(int t=0;t<2;t++){
      int cc = rr*2 + t;
      #pragma unroll
      for(int wo=0;wo<8;wo++){
        int r = wo*8 + r8;
        async16(Kt + base + (size_t)r*SEQ + cc*64, (void*)&Ks[t][wo*512]);
        async16(Vt + base + (size_t)r*SEQ + cc*64, (void*)&Vs[t][wo*512]);
      }
    }
    asm volatile("s_waitcnt vmcnt(0)" ::: "memory");
    #pragma unroll
    for(int t=0;t<2;t++){
      #pragma unroll
      for(int ks=0; ks<2; ks++){
        const int ch = ((ks*4 + kc4) ^ x7)*8;
        short8 a[4], b[4];
        #pragma unroll
        for(int i=0;i<4;i++) a[i]=*(const short8*)&Vs[t][(l15+i*16)*64 + ch];
        #pragma unroll
        for(int j=0;j<4;j++) b[j]=*(const short8*)&Ks[t][(l15+j*16)*64 + ch];
        #pragma unroll
        for(int j=0;j<4;j++)
          #pragma unroll
          for(int e8=0;e8<8;e8++) zacc[j] += b2f((unsigned short)b[j][e8]);
        #pragma unroll
        for(int i=0;i<4;i++)
          #pragma unroll
          for(int j=0;j<4;j++)
            acc[i][j]=__builtin_amdgcn_mfma_f32_16x16x32_bf16(a[i],b[j],acc[i][j],0,0,0);
      }
    }
  }
  // z: lanes l, l+16, l+32, l+48 hold disjoint n-chunks of d = j*16+l15
  #pragma unroll
  for(int j=0;j<4;j++){
    float v = zacc[j];
    v += __shfl_down(v, 32);
    v += __shfl_down(v, 16);
    if(lane<16) zp[(size_t)blk*64 + j*16 + lane] = v;
  }
  float* kvd = kvp + (size_t)blk*4096;
  #pragma unroll
  for(int i=0;i<4;i++)
    #pragma unroll
    for(int j=0;j<4;j++)
      #pragma unroll
      for(int r=0;r<4;r++)
        kvd[(i*16 + kc4*4 + r)*64 + j*16 + l15] = acc[i][j][r];
}

// reduce 16 partials -> kvtb[bh][80][64] bf16: rows 0..63 kvT, row 64 = z, 65..79 = 0
__global__ void kvz_reduce_kernel(const float* __restrict__ kvp, const float* __restrict__ zp,
                                  unsigned short* __restrict__ kvtb){
  int bh = blockIdx.x, t = threadIdx.x;
  for(int idx=t; idx<5120; idx+=256){
    int e = idx>>6, d = idx&63;
    float s = 0.f;
    if(e < 64){
      for(int c=0;c<16;c++) s += kvp[((size_t)bh*16+c)*4096 + e*64 + d];
    } else if(e == 64){
      for(int c=0;c<16;c++) s += zp[((size_t)bh*16+c)*64 + d];
    }
    kvtb[(size_t)bh*5120 + idx] = f2b(s);
  }
}

// ---------------- y[m][e] = (qf @ kvT^T)/max(qf.z,eps) via MFMA, K=64 ----------
// B-tile = kvtb[bh][80][64]: rows 0..63 -> y cols, row 64 -> denominator col.
__global__ __launch_bounds__(256) void y_gemm_kernel(
    const unsigned short* __restrict__ qb, const unsigned short* __restrict__ kvtb,
    unsigned short* __restrict__ ybuf)
{
  __shared__ __align__(16) unsigned short As[128*64];
  __shared__ __align__(16) unsigned short Bs[80*64];
  const int tid = threadIdx.x, lane = tid&63, wave = tid>>6;
  const int bh = blockIdx.y, b = bh>>4, h = bh&15;
  const int m0 = blockIdx.x*128;
  const int r8 = lane>>3, gch = ((lane&7)^r8)*8;
  const unsigned short* qbase = qb + ((size_t)(b*SEQ + m0))*1024 + h*64 + gch;
  #pragma unroll
  for(int it=0; it<4; it++){
    int wo = wave*4 + it, r = wo*8 + r8;
    async16(qbase + (size_t)r*1024, (void*)&As[wo*512]);
  }
  const unsigned short* kvb = kvtb + (size_t)bh*5120 + gch;
  #pragma unroll
  for(int it=0; it<3; it++){
    int wo = wave + it*4;
    if(wo < 10){ int r = wo*8 + r8; async16(kvb + r*64, (void*)&Bs[wo*512]); }
  }
  __syncthreads();
  const int l15 = lane&15, kc4 = lane>>4, x7 = lane&7;
  f32x4 acc[2][5];
  #pragma unroll
  for(int i=0;i<2;i++)
    #pragma unroll
    for(int j=0;j<5;j++) acc[i][j]=(f32x4)(0.f);
  #pragma unroll
  for(int ks=0; ks<2; ks++){
    const int ch = ((ks*4 + kc4) ^ x7)*8;
    short8 a[2], bb[5];
    #pragma unroll
    for(int i=0;i<2;i++) a[i]=*(const short8*)&As[(wave*32 + i*16 + l15)*64 + ch];
    #pragma unroll
    for(int j=0;j<5;j++) bb[j]=*(const short8*)&Bs[(j*16 + l15)*64 + ch];
    #pragma unroll
    for(int i=0;i<2;i++)
      #pragma unroll
      for(int j=0;j<5;j++)
        acc[i][j]=__builtin_amdgcn_mfma_f32_16x16x32_bf16(a[i],bb[j],acc[i][j],0,0,0);
  }
  #pragma unroll
  for(int i=0;i<2;i++){
    #pragma unroll
    for(int r=0;r<4;r++){
      float den = __shfl(acc[i][4][r], lane & 48);   // col 64 lives at l15==0
      float inv = 1.f/fmaxf(den, 1e-6f);
      size_t m = (size_t)(b*SEQ + m0 + wave*32 + i*16 + kc4*4 + r);
      #pragma unroll
      for(int j=0;j<4;j++)
        ybuf[m*1024 + h*64 + j*16 + l15] = f2b(acc[i][j][r]*inv);
    }
  }
}

extern "C" void kernel_launch(void* const* d_in, const int* in_sizes, int n_in,
                              void* d_out, int out_size, void* d_ws, size_t ws_size,
                              hipStream_t stream)
{
  const float* src   = (const float*)d_in[0];
  const void*  mask  = d_in[1];
  const float* qkv_w = (const float*)d_in[2];
  const float* qkv_b = (const float*)d_in[3];
  const float* out_w = (const float*)d_in[4];
  const float* out_b = (const float*)d_in[5];
  const float* w1    = (const float*)d_in[6];
  const float* b1    = (const float*)d_in[7];
  const float* w2    = (const float*)d_in[8];
  const float* b2    = (const float*)d_in[9];
  const float* ln1g  = (const float*)d_in[10];
  const float* ln1b  = (const float*)d_in[11];
  const float* ln2g  = (const float*)d_in[12];
  const float* ln2b  = (const float*)d_in[13];
  float* out = (float*)d_out;
  char* ws = (char*)d_ws;

  // workspace layout
  size_t o = 0;
  o += 256;                                       // (reserved)
  float* validf = (float*)(ws+o);                 o += (size_t)MTOK*4;
  unsigned short* wqb = (unsigned short*)(ws+o);  o += (size_t)3072*1024*2;
  unsigned short* wob = (unsigned short*)(ws+o);  o += (size_t)1024*1024*2;
  unsigned short* w1b = (unsigned short*)(ws+o);  o += (size_t)4096*1024*2;
  unsigned short* w2b = (unsigned short*)(ws+o);  o += (size_t)1024*4096*2;
  unsigned short* bufA = (unsigned short*)(ws+o); o += (size_t)MTOK*1024*2;       // ln1 -> y -> ln2
  char* R = ws+o;                                 o += (size_t)MTOK*4096*2;       // attn bufs, then h
  unsigned short* qb  = (unsigned short*)R;                                        // 67 MB phi(q) [m][1024]
  unsigned short* ktb = (unsigned short*)(R + (size_t)MTOK*1024*2);                // 67 MB K^T [bh][64][4096]
  unsigned short* vtb = (unsigned short*)(R + (size_t)MTOK*2048*2);                // 67 MB V^T
  float* kvp = (float*)(R + (size_t)MTOK*3072*2);                                  // 33.5 MB partials (fits R tail)
  unsigned short* hbuf = (unsigned short*)R;                                       // FFN h aliases R
  float* zp = (float*)(ws+o);                     o += (size_t)2048*64*4;          // 0.5 MB z partials
  unsigned short* kvtb = (unsigned short*)(ws+o); o += (size_t)128*5120*2;         // 1.25 MB kvT+z bf16

  decode_mask_kernel<<<MTOK/256,256,0,stream>>>(mask, validf);
  cast_all_kernel<<<12288,256,0,stream>>>(qkv_w, out_w, w1, w2, wqb, wob, w1b, w2b);

  ln_kernel<<<MTOK,256,0,stream>>>(src, ln1g, ln1b, bufA);
  gemm_bt<0><<<dim3(3072/128, MTOK/128),256,0,stream>>>(bufA, wqb, qkv_b, validf, nullptr, qb, ktb, vtb, MTOK,3072,1024);
  kvz_mfma_kernel<<<2048,64,0,stream>>>(ktb, vtb, kvp, zp);
  kvz_reduce_kernel<<<128,256,0,stream>>>(kvp, zp, kvtb);
  y_gemm_kernel<<<dim3(SEQ/128,128),256,0,stream>>>(qb, kvtb, bufA);
  gemm_bt<1><<<dim3(1024/128, MTOK/128),256,0,stream>>>(bufA, wob, out_b, src, out, nullptr, nullptr, nullptr, MTOK,1024,1024);
  ln_kernel<<<MTOK,256,0,stream>>>(out, ln2g, ln2b, bufA);
  gemm_bt<2><<<dim3(4096/128, MTOK/128),256,0,stream>>>(bufA, w1b, b1, nullptr, nullptr, hbuf, nullptr, nullptr, MTOK,4096,1024);
  gemm_bt<3><<<dim3(1024/128, MTOK/128),256,0,stream>>>(hbuf, w2b, b2, nullptr, out, nullptr, nullptr, nullptr, MTOK,1024,4096);
}

// Round 8
// 1306.234 us; speedup vs baseline: 1.1148x; 1.0012x over previous
//
#include <hip/hip_runtime.h>
#include <cmath>
#include <cstdint>

// Problem constants (B=8, N=4096, C=1024, H=16, D=64, FF=4096)
#define MTOK 32768   // B*N tokens
#define CDIM 1024
#define SEQ  4096
#define NHEAD 16
#define HDIM 64
#define FFDIM 4096

typedef __attribute__((ext_vector_type(8))) short short8;   // 8 bf16 (4 VGPRs)
typedef __attribute__((ext_vector_type(4))) float f32x4;

static __device__ __forceinline__ float b2f(unsigned short u){
  union { unsigned int i; float f; } c; c.i = ((unsigned int)u)<<16; return c.f;
}
static __device__ __forceinline__ unsigned short f2b(float f){
  union { float f; unsigned int i; } c; c.f = f;
  return (unsigned short)((c.i + 0x7fffu + ((c.i>>16)&1u)) >> 16);  // RNE
}
// gelu_exact via A&S 7.1.26 erf (|eps|<=1.5e-7, far below bf16 quantum)
static __device__ __forceinline__ float fast_gelu(float v){
  float s = v*0.70710678118654752f;
  float a = fabsf(s);
  float t = 1.f/(1.f + 0.3275911f*a);
  float p = t*(0.254829592f + t*(-0.284496736f + t*(1.421413741f +
            t*(-1.453152027f + t*1.061405429f))));
  float erfa = 1.f - p*__expf(-a*a);
  float er = (s<0.f)? -erfa : erfa;
  return 0.5f*v*(1.f+er);
}
// async global->LDS, 16B/lane; LDS dest = wave-uniform base + lane*16
static __device__ __forceinline__ void async16(const void* g, void* l){
  __builtin_amdgcn_global_load_lds((const __attribute__((address_space(1))) void*)g,
                                   (__attribute__((address_space(3))) void*)l, 16, 0, 0);
}

// ---------------- mask decode with per-block dtype detection ----------------
__global__ void decode_mask_kernel(const void* __restrict__ m, float* __restrict__ validf){
  __shared__ int any;
  if(threadIdx.x==0) any=0;
  __syncthreads();
  const unsigned int* mu = (const unsigned int*)m;
  int loc=0;
  for(int i=threadIdx.x;i<8192;i+=256) if(mu[i]>1u) loc=1;
  if(loc) atomicOr(&any,1);
  __syncthreads();
  int i = blockIdx.x*256 + threadIdx.x;   // grid covers MTOK exactly
  int pad = any ? (int)((const unsigned char*)m)[i] : ((const int*)m)[i];
  validf[i] = pad ? 0.f : 1.f;
}

// ---------------- fp32 -> bf16 cast, all four weights in one launch ----------------
__global__ void cast_all_kernel(const float* __restrict__ a, const float* __restrict__ b,
                                const float* __restrict__ c, const float* __restrict__ d,
                                unsigned short* __restrict__ oa, unsigned short* __restrict__ ob,
                                unsigned short* __restrict__ oc, unsigned short* __restrict__ od){
  long i = ((long)blockIdx.x*256 + threadIdx.x)*4;   // total 12582912 elems -> 12288 blocks
  const float* x; unsigned short* y; long off;
  if(i < 3145728){ x=a; y=oa; off=i; }
  else if(i < 4194304){ x=b; y=ob; off=i-3145728; }
  else if(i < 8388608){ x=c; y=oc; off=i-4194304; }
  else { x=d; y=od; off=i-8388608; }
  float4 v = *(const float4*)(x+off);
  ushort4 o; o.x=f2b(v.x); o.y=f2b(v.y); o.z=f2b(v.z); o.w=f2b(v.w);
  *(ushort4*)(y+off)=o;
}

// ---------------- LayerNorm (C=1024) -> bf16 ----------------
__global__ __launch_bounds__(256) void ln_kernel(const float* __restrict__ x,
    const float* __restrict__ g, const float* __restrict__ bt, unsigned short* __restrict__ out){
  int row = blockIdx.x, t = threadIdx.x;
  const float* xr = x + (size_t)row*CDIM;
  float4 v = *(const float4*)(xr + t*4);
  float s1 = v.x+v.y+v.z+v.w;
  float s2 = v.x*v.x+v.y*v.y+v.z*v.z+v.w*v.w;
  #pragma unroll
  for(int off=32; off>0; off>>=1){ s1+=__shfl_down(s1,off); s2+=__shfl_down(s2,off); }
  __shared__ float a1[4], a2[4];
  __shared__ float mu_s, rs_s;
  if((t&63)==0){ a1[t>>6]=s1; a2[t>>6]=s2; }
  __syncthreads();
  if(t==0){
    float u1=a1[0]+a1[1]+a1[2]+a1[3], u2=a2[0]+a2[1]+a2[2]+a2[3];
    float mu=u1*(1.f/CDIM);
    mu_s=mu; rs_s=rsqrtf(u2*(1.f/CDIM)-mu*mu+1e-5f);
  }
  __syncthreads();
  float mu=mu_s, rs=rs_s;
  float4 gg=*(const float4*)(g+t*4), bb=*(const float4*)(bt+t*4);
  ushort4 o;
  o.x=f2b((v.x-mu)*rs*gg.x+bb.x);
  o.y=f2b((v.y-mu)*rs*gg.y+bb.y);
  o.z=f2b((v.z-mu)*rs*gg.z+bb.z);
  o.w=f2b((v.w-mu)*rs*gg.w+bb.w);
  *(ushort4*)(out+(size_t)row*CDIM+t*4)=o;
}

// ---------------- GEMM: C[M,N] = A[M,K] * Bw[N,K]^T, bf16 in, fused epilogue ----
// known-good 128x128 m97-structure; LDS XOR-chunk swizzle, global_load_lds x16.
// Grouped XCD walk: 8 A-panels x 4 B-panels concurrent footprint per XCD <= L2.
// 16x16x32 MFMA only (32x32 has a structural LDS bank conflict here, r5).
// MODE 0: QKV -> q: phi(q) -> Cb[m][1024]; k: phi(k)*valid -> Kt[bh][d][pos];
//         v: v*valid -> Vt[bh][d][pos]  (K/V stored TRANSPOSED for MFMA kvz)
// MODE 1: XRES -> Cf[m,N] = acc + bias + extra[m,N]   (out-proj + residual, Cf=d_out)
// MODE 2: GELU -> Cb[m,N] = bf16(gelu_exact(acc+bias))
// MODE 3: ADD  -> Cf[m,N] += acc + bias               (FFN2 accumulate into x)
// FFN (MODE 2/3) is launched in m-halves, interleaved 1(h0),2(h0),1(h1),2(h1):
// each h-half (134 MB) stays Infinity-Cache-resident between producer and
// consumer, turning FFN2's A-panel staging from HBM-latency to L3-latency.
template<int MODE>
__global__ __launch_bounds__(256,2) void gemm_bt(
    const unsigned short* __restrict__ A, const unsigned short* __restrict__ Bw,
    const float* __restrict__ bias, const float* __restrict__ extra,
    float* __restrict__ Cf, unsigned short* __restrict__ Cb,
    unsigned short* __restrict__ Kt, unsigned short* __restrict__ Vt,
    int M, int N, int K)
{
  __shared__ __align__(16) unsigned short As[128*64];
  __shared__ __align__(16) unsigned short Bs[128*64];
  const int tid = threadIdx.x;
  const int wave = tid>>6, lane = tid&63;
  const int wm = wave>>1, wn = wave&1;          // 2x2 wave grid, 64x64 per wave
  // XCD-aware grouped remap (gridDim.x%4==0, total%8==0; bijective for
  // gridDim.y in {128,256} -- verified nx<gx, ny<gridDim.y, count exact)
  const int gx  = gridDim.x;
  const int f   = blockIdx.y * gx + blockIdx.x;
  const int xcd = f & 7;
  const int kk  = f >> 3;
  const int idx = kk & 31, g = kk >> 5;
  const int nq  = gx >> 2;
  const int gxq = g % nq, gy = g / nq;
  const int nx  = gxq*4 + (idx>>3);
  const int ny  = (gy*8 + (idx&7))*8 + xcd;
  const int m0 = ny*128, n0 = nx*128;
  const int lrow = lane>>3;                     // 0..7 rows within a wave-op
  const int gcol = (((lane&7) ^ lrow))*8;       // swizzled global chunk for staging

  f32x4 acc[4][4];
  #pragma unroll
  for(int i=0;i<4;i++)
    #pragma unroll
    for(int j=0;j<4;j++) acc[i][j]=(f32x4)(0.f);

  const int ar = wm*64 + (lane&15);             // A frag row in tile
  const int br = wn*64 + (lane&15);             // B frag row in tile
  const int kc = lane>>4;                       // k chunk sub-index (0..3)
  const int xorv = lane&7;                      // row&7 == lane&7 for all frags

  for(int kt=0; kt<K; kt+=64){
    #pragma unroll
    for(int it=0; it<4; it++){
      int wo = wave*4+it;                       // wave-op 0..15, 8 rows each
      int r  = wo*8 + lrow;
      async16(A  + (size_t)(m0+r)*K + kt + gcol, (void*)&As[wo*512]);
      async16(Bw + (size_t)(n0+r)*K + kt + gcol, (void*)&Bs[wo*512]);
    }
    __syncthreads();   // compiler drains vmcnt before s_barrier -> tiles ready
    #pragma unroll
    for(int ks=0; ks<2; ks++){
      const int ch = ((ks*4 + kc) ^ xorv)*8;    // swizzled LDS chunk offset
      short8 a[4], b[4];
      #pragma unroll
      for(int i=0;i<4;i++){
        a[i]=*(const short8*)&As[(ar+i*16)*64 + ch];
        b[i]=*(const short8*)&Bs[(br+i*16)*64 + ch];
      }
      #pragma unroll
      for(int i=0;i<4;i++)
        #pragma unroll
        for(int j=0;j<4;j++)
          acc[i][j]=__builtin_amdgcn_mfma_f32_16x16x32_bf16(a[i],b[j],acc[i][j],0,0,0);
    }
    __syncthreads();
  }
  // epilogue: C/D layout col=lane&15, row=(lane>>4)*4+reg
  const int rbase = m0 + wm*64 + (lane>>4)*4;
  const int cbase = n0 + wn*64 + (lane&15);
  if(MODE==0){
    #pragma unroll
    for(int mi=0;mi<4;mi++){
      int mrow = rbase + mi*16;
      float4 vld = *(const float4*)(extra + mrow);   // validf, mrow%4==0
      float vv[4] = {vld.x, vld.y, vld.z, vld.w};
      #pragma unroll
      for(int ni=0;ni<4;ni++){
        int n = cbase + ni*16;
        float bs = bias[n];
        int part = n>>10;                            // 0=q,1=k,2=v (tile never straddles)
        if(part==0){
          #pragma unroll
          for(int i=0;i<4;i++){
            float v = acc[mi][ni][i] + bs;
            float p = (v>0.f)? (v+1.f) : __expf(v);  // phi = elu+1
            Cb[(size_t)(mrow+i)*1024 + n] = f2b(p);  // qb[m][1024]
          }
        } else {
          int d = n & 63, hh = (n>>6) & 15;
          int bb_ = mrow >> 12, pos = mrow & 4095;   // pos%4==0 -> aligned ushort4
          unsigned short* dst = (part==1? Kt : Vt)
              + (((size_t)(bb_*16+hh)*64 + d)*SEQ + pos);
          ushort4 o;
          #pragma unroll
          for(int i=0;i<4;i++){
            float v = acc[mi][ni][i] + bs;
            float r = (part==1)? (((v>0.f)?(v+1.f):__expf(v))*vv[i]) : (v*vv[i]);
            ((unsigned short*)&o)[i] = f2b(r);
          }
          *(ushort4*)dst = o;                        // 4 consecutive seq positions
        }
      }
    }
  } else {
    #pragma unroll
    for(int mi=0;mi<4;mi++){
      #pragma unroll
      for(int i=0;i<4;i++){
        int m = rbase + mi*16 + i;
        #pragma unroll
        for(int ni=0;ni<4;ni++){
          int n = cbase + ni*16;
          float v = acc[mi][ni][i] + bias[n];
          if(MODE==1){
            size_t off=(size_t)m*N+n;
            Cf[off] = v + extra[off];
          } else if(MODE==2){
            Cb[(size_t)m*N+n] = f2b(fast_gelu(v));
          } else {
            size_t off=(size_t)m*N+n;
            Cf[off] += v;
          }
        }
      }
    }
  }
}

// ---------------- kvT[e][d] = sum_n v[n][e]*kf[n][d], z[d] = sum_n kf[n][d] ----
__global__ __launch_bounds__(64) void kvz_mfma_kernel(
    const unsigned short* __restrict__ Kt, const unsigned short* __restrict__ Vt,
    float* __restrict__ kvp, float* __restrict__ zp)
{
  __shared__ __align__(16) unsigned short Ks[2][64*64];
  __shared__ __align__(16) unsigned short Vs[2][64*64];
  const int blk = blockIdx.x;             // 0..2047
  const int bh = blk>>4, kcn = blk&15;    // n-slice of 256
  const int n0 = kcn*256;
  const int lane = threadIdx.x;
  const int r8 = lane>>3;
  const int gch = ((lane&7) ^ r8)*8;
  const size_t base = (size_t)bh*64*SEQ + n0 + gch;
  f32x4 acc[4][4];
  #pragma unroll
  for(int i=0;i<4;i++)
    #pragma unroll
    for(int j=0;j<4;j++) acc[i][j]=(f32x4)(0.f);
  float zacc[4]={0.f,0.f,0.f,0.f};
  const int l15 = lane&15, kc4 = lane>>4, x7 = lane&7;
  for(int rr=0; rr<2; rr++){
    if(rr) asm volatile("s_waitcnt lgkmcnt(0)" ::: "memory");  // ds_reads done before DMA overwrite
    #pragma unroll
    for(int t=0;t<2;t++){
      int cc = rr*2 + t;
      #pragma unroll
      for(int wo=0;wo<8;wo++){
        int r = wo*8 + r8;
        async16(Kt + base + (size_t)r*SEQ + cc*64, (void*)&Ks[t][wo*512]);
        async16(Vt + base + (size_t)r*SEQ + cc*64, (void*)&Vs[t][wo*512]);
      }
    }
    asm volatile("s_waitcnt vmcnt(0)" ::: "memory");
    #pragma unroll
    for(int t=0;t<2;t++){
      #pragma unroll
      for(int ks=0; ks<2; ks++){
        const int ch = ((ks*4 + kc4) ^ x7)*8;
        short8 a[4], b[4];
        #pragma unroll
        for(int i=0;i<4;i++) a[i]=*(const short8*)&Vs[t][(l15+i*16)*64 + ch];
        #pragma unroll
        for(int j=0;j<4;j++) b[j]=*(const short8*)&Ks[t][(l15+j*16)*64 + ch];
        #pragma unroll
        for(int j=0;j<4;j++)
          #pragma unroll
          for(int e8=0;e8<8;e8++) zacc[j] += b2f((unsigned short)b[j][e8]);
        #pragma unroll
        for(int i=0;i<4;i++)
          #pragma unroll
          for(int j=0;j<4;j++)
            acc[i][j]=__builtin_amdgcn_mfma_f32_16x16x32_bf16(a[i],b[j],acc[i][j],0,0,0);
      }
    }
  }
  // z: lanes l, l+16, l+32, l+48 hold disjoint n-chunks of d = j*16+l15
  #pragma unroll
  for(int j=0;j<4;j++){
    float v = zacc[j];
    v += __shfl_down(v, 32);
    v += __shfl_down(v, 16);
    if(lane<16) zp[(size_t)blk*64 + j*16 + lane] = v;
  }
  float* kvd = kvp + (size_t)blk*4096;
  #pragma unroll
  for(int i=0;i<4;i++)
    #pragma unroll
    for(int j=0;j<4;j++)
      #pragma unroll
      for(int r=0;r<4;r++)
        kvd[(i*16 + kc4*4 + r)*64 + j*16 + l15] = acc[i][j][r];
}

// reduce 16 partials -> kvtb[bh][80][64] bf16: rows 0..63 kvT, row 64 = z, 65..79 = 0
__global__ void kvz_reduce_kernel(const float* __restrict__ kvp, const float* __restrict__ zp,
                                  unsigned short* __restrict__ kvtb){
  int bh = blockIdx.x, t = threadIdx.x;
  for(int idx=t; idx<5120; idx+=256){
    int e = idx>>6, d = idx&63;
    float s = 0.f;
    if(e < 64){
      for(int c=0;c<16;c++) s += kvp[((size_t)bh*16+c)*4096 + e*64 + d];
    } else if(e == 64){
      for(int c=0;c<16;c++) s += zp[((size_t)bh*16+c)*64 + d];
    }
    kvtb[(size_t)bh*5120 + idx] = f2b(s);
  }
}

// ---------------- y[m][e] = (qf @ kvT^T)/max(qf.z,eps) via MFMA, K=64 ----------
__global__ __launch_bounds__(256) void y_gemm_kernel(
    const unsigned short* __restrict__ qb, const unsigned short* __restrict__ kvtb,
    unsigned short* __restrict__ ybuf)
{
  __shared__ __align__(16) unsigned short As[128*64];
  __shared__ __align__(16) unsigned short Bs[80*64];
  const int tid = threadIdx.x, lane = tid&63, wave = tid>>6;
  const int bh = blockIdx.y, b = bh>>4, h = bh&15;
  const int m0 = blockIdx.x*128;
  const int r8 = lane>>3, gch = ((lane&7)^r8)*8;
  const unsigned short* qbase = qb + ((size_t)(b*SEQ + m0))*1024 + h*64 + gch;
  #pragma unroll
  for(int it=0; it<4; it++){
    int wo = wave*4 + it, r = wo*8 + r8;
    async16(qbase + (size_t)r*1024, (void*)&As[wo*512]);
  }
  const unsigned short* kvb = kvtb + (size_t)bh*5120 + gch;
  #pragma unroll
  for(int it=0; it<3; it++){
    int wo = wave + it*4;
    if(wo < 10){ int r = wo*8 + r8; async16(kvb + r*64, (void*)&Bs[wo*512]); }
  }
  __syncthreads();
  const int l15 = lane&15, kc4 = lane>>4, x7 = lane&7;
  f32x4 acc[2][5];
  #pragma unroll
  for(int i=0;i<2;i++)
    #pragma unroll
    for(int j=0;j<5;j++) acc[i][j]=(f32x4)(0.f);
  #pragma unroll
  for(int ks=0; ks<2; ks++){
    const int ch = ((ks*4 + kc4) ^ x7)*8;
    short8 a[2], bb[5];
    #pragma unroll
    for(int i=0;i<2;i++) a[i]=*(const short8*)&As[(wave*32 + i*16 + l15)*64 + ch];
    #pragma unroll
    for(int j=0;j<5;j++) bb[j]=*(const short8*)&Bs[(j*16 + l15)*64 + ch];
    #pragma unroll
    for(int i=0;i<2;i++)
      #pragma unroll
      for(int j=0;j<5;j++)
        acc[i][j]=__builtin_amdgcn_mfma_f32_16x16x32_bf16(a[i],bb[j],acc[i][j],0,0,0);
  }
  #pragma unroll
  for(int i=0;i<2;i++){
    #pragma unroll
    for(int r=0;r<4;r++){
      float den = __shfl(acc[i][4][r], lane & 48);   // col 64 lives at l15==0
      float inv = 1.f/fmaxf(den, 1e-6f);
      size_t m = (size_t)(b*SEQ + m0 + wave*32 + i*16 + kc4*4 + r);
      #pragma unroll
      for(int j=0;j<4;j++)
        ybuf[m*1024 + h*64 + j*16 + l15] = f2b(acc[i][j][r]*inv);
    }
  }
}

extern "C" void kernel_launch(void* const* d_in, const int* in_sizes, int n_in,
                              void* d_out, int out_size, void* d_ws, size_t ws_size,
                              hipStream_t stream)
{
  const float* src   = (const float*)d_in[0];
  const void*  mask  = d_in[1];
  const float* qkv_w = (const float*)d_in[2];
  const float* qkv_b = (const float*)d_in[3];
  const float* out_w = (const float*)d_in[4];
  const float* out_b = (const float*)d_in[5];
  const float* w1    = (const float*)d_in[6];
  const float* b1    = (const float*)d_in[7];
  const float* w2    = (const float*)d_in[8];
  const float* b2    = (const float*)d_in[9];
  const float* ln1g  = (const float*)d_in[10];
  const float* ln1b  = (const float*)d_in[11];
  const float* ln2g  = (const float*)d_in[12];
  const float* ln2b  = (const float*)d_in[13];
  float* out = (float*)d_out;
  char* ws = (char*)d_ws;

  // workspace layout
  size_t o = 0;
  o += 256;                                       // (reserved)
  float* validf = (float*)(ws+o);                 o += (size_t)MTOK*4;
  unsigned short* wqb = (unsigned short*)(ws+o);  o += (size_t)3072*1024*2;
  unsigned short* wob = (unsigned short*)(ws+o);  o += (size_t)1024*1024*2;
  unsigned short* w1b = (unsigned short*)(ws+o);  o += (size_t)4096*1024*2;
  unsigned short* w2b = (unsigned short*)(ws+o);  o += (size_t)1024*4096*2;
  unsigned short* bufA = (unsigned short*)(ws+o); o += (size_t)MTOK*1024*2;       // ln1 -> y -> ln2
  char* R = ws+o;                                 o += (size_t)MTOK*4096*2;       // attn bufs, then h
  unsigned short* qb  = (unsigned short*)R;                                        // 67 MB phi(q) [m][1024]
  unsigned short* ktb = (unsigned short*)(R + (size_t)MTOK*1024*2);                // 67 MB K^T [bh][64][4096]
  unsigned short* vtb = (unsigned short*)(R + (size_t)MTOK*2048*2);                // 67 MB V^T
  float* kvp = (float*)(R + (size_t)MTOK*3072*2);                                  // 33.5 MB partials (fits R tail)
  unsigned short* hbuf = (unsigned short*)R;                                       // FFN h aliases R
  float* zp = (float*)(ws+o);                     o += (size_t)2048*64*4;          // 0.5 MB z partials
  unsigned short* kvtb = (unsigned short*)(ws+o); o += (size_t)128*5120*2;         // 1.25 MB kvT+z bf16

  decode_mask_kernel<<<MTOK/256,256,0,stream>>>(mask, validf);
  cast_all_kernel<<<12288,256,0,stream>>>(qkv_w, out_w, w1, w2, wqb, wob, w1b, w2b);

  ln_kernel<<<MTOK,256,0,stream>>>(src, ln1g, ln1b, bufA);
  gemm_bt<0><<<dim3(3072/128, MTOK/128),256,0,stream>>>(bufA, wqb, qkv_b, validf, nullptr, qb, ktb, vtb, MTOK,3072,1024);
  kvz_mfma_kernel<<<2048,64,0,stream>>>(ktb, vtb, kvp, zp);
  kvz_reduce_kernel<<<128,256,0,stream>>>(kvp, zp, kvtb);
  y_gemm_kernel<<<dim3(SEQ/128,128),256,0,stream>>>(qb, kvtb, bufA);
  gemm_bt<1><<<dim3(1024/128, MTOK/128),256,0,stream>>>(bufA, wob, out_b, src, out, nullptr, nullptr, nullptr, MTOK,1024,1024);
  ln_kernel<<<MTOK,256,0,stream>>>(out, ln2g, ln2b, bufA);
  // FFN in m-halves, interleaved so each h-half (134 MB) is L3-resident when
  // FFN2 consumes it (h full = 268 MB > 256 MB Infinity Cache).
  const size_t HM = MTOK/2;   // 16384 rows per half
  for(int half=0; half<2; ++half){
    const unsigned short* aH = bufA + (size_t)half*HM*1024;
    unsigned short* hH = hbuf + (size_t)half*HM*4096;
    float* outH = out + (size_t)half*HM*1024;
    gemm_bt<2><<<dim3(4096/128, HM/128),256,0,stream>>>(aH, w1b, b1, nullptr, nullptr, hH, nullptr, nullptr, HM,4096,1024);
    gemm_bt<3><<<dim3(1024/128, HM/128),256,0,stream>>>(hH, w2b, b2, nullptr, outH, nullptr, nullptr, nullptr, HM,1024,4096);
  }
}